// Round 12
// baseline (312.909 us; speedup 1.0000x reference)
//
#include <hip/hip_runtime.h>
#include <math.h>
#include <stdint.h>

// PaiNN QM encoder, round 12.
//   U = V_JK @ W1b  (N,3,256)   T = b1 + n_i@W1c + S_JK@W1d  (N,256)
//   per edge: x = silu(T[i] + e_pi@W1a + r_hat.U[i]); m = (silu(x@W2+b2))@w3+b3
// r12: kB1 occupancy push -- W2 fragments re-read from L2 each use (frees 64
// VGPR), per-mt sequential MFMA1/pairs, __launch_bounds__(256,6) -> 6 blk/CU.
// kHist merged into kAW tail; kScatter merged into kA2 tail (2 fewer launches).

#define L_DIM 6
#define F_DIM 256
#define FH_DIM 128
#define DRBF 32
#define CUTOFF_F 4.0f
#define PI_F 3.14159265358979323846f

using bf16x8 = __attribute__((ext_vector_type(8))) short;
using f32x4v = __attribute__((ext_vector_type(4))) float;

__device__ __forceinline__ float silu_f(float x){ return x / (1.f + __expf(-x)); }

__device__ __forceinline__ unsigned short f2bf(float f){
    uint32_t u = __float_as_uint(f);
    uint32_t r = (u + 0x7fffu + ((u >> 16) & 1u)) >> 16;   // RNE
    return (unsigned short)r;
}

// ---------------- kPrep: weight transpose/convert + output/CSR zeroing ----------------
__global__ __launch_bounds__(256) void kPrep(
    const float* __restrict__ msg_w1, const float* __restrict__ msg_w2,
    const float* __restrict__ attn_w1,
    unsigned short* __restrict__ w1bt, unsigned short* __restrict__ w1cdt,
    unsigned short* __restrict__ w2t, unsigned short* __restrict__ wA1t,
    float* __restrict__ rho, int P, int* __restrict__ cntpos, int CN)
{
    int idx = blockIdx.x * 256 + threadIdx.x;
    if (idx < 65536){
        int k = idx >> 8, j = idx & 255;
        w1bt[(size_t)j * 256 + k] = f2bf(msg_w1[(size_t)(DRBF + k) * F_DIM + j]);
    } else if (idx < 196608){
        int i2 = idx - 65536;
        int k = i2 >> 8, j = i2 & 255;
        w1cdt[(size_t)j * 512 + k] = f2bf(msg_w1[(size_t)(DRBF + 256 + k) * F_DIM + j]);
    } else if (idx < 229376){
        int i3 = idx - 196608;
        int k = i3 >> 7, h = i3 & 127;
        w2t[(size_t)h * 256 + k] = f2bf(msg_w2[(size_t)k * FH_DIM + h]);
    } else if (idx < 262144){
        int i4 = idx - 229376;
        int j = i4 >> 8, k = i4 & 255;
        wA1t[(size_t)j * 256 + k] = f2bf(attn_w1[(size_t)k * FH_DIM + j]);
    } else if (idx < 262144 + 32768){
        int i5 = idx - 262144;
        if (i5 < P) rho[i5] = 0.f;
    } else {
        int i6 = idx - 262144 - 32768;
        if (i6 < CN) cntpos[i6] = 0;
    }
}

// ---------------- kAW: fused attention + hist tail (r11 + kHist merge) ----------------
__global__ __launch_bounds__(256) void kAW(
    const float* __restrict__ s_stack, const float* __restrict__ v_stack,
    const unsigned short* __restrict__ wA1t,
    const float* __restrict__ attn_b1, const float* __restrict__ attn_w2,
    unsigned short* __restrict__ VJKb, unsigned short* __restrict__ NISb,
    const int* __restrict__ pe, int* __restrict__ cnt, int E, int N)
{
    __shared__ float part[4][48];
    __shared__ float aw_l[8][8];

    const int t  = threadIdx.x;
    const int l  = t & 63;
    const int w  = t >> 6;
    const int lm = l & 15, lq = l >> 4;

    bf16x8 bfr[2][8];
    #pragma unroll
    for (int nt2 = 0; nt2 < 2; nt2++){
        const int col = w*32 + nt2*16 + lm;
        #pragma unroll
        for (int kb = 0; kb < 8; kb++)
            bfr[nt2][kb] = *(const bf16x8*)(wA1t + (size_t)col * 256 + kb*32 + lq*8);
    }
    const float b1a = attn_b1[w*32 + lm];
    const float b1b = attn_b1[w*32 + 16 + lm];
    const float w2a = attn_w2[w*32 + lm];
    const float w2b = attn_w2[w*32 + 16 + lm];

    const int n0 = blockIdx.x * 8;
    const size_t rbase = (size_t)n0 * L_DIM;
    const size_t rmax  = (size_t)N * L_DIM - 1;

    // ---- phase 1: logits (48 rows = 3 m-tiles) ----
    #pragma unroll
    for (int mt = 0; mt < 3; mt++){
        const size_t r0 = rbase + mt * 16;
        bf16x8 af[8];
        #pragma unroll
        for (int kb = 0; kb < 8; kb++){
            size_t row = r0 + lm; if (row > rmax) row = rmax;
            const float* ap = s_stack + row * 256 + kb*32 + lq*8;
            float4 fa = *(const float4*)ap;
            float4 fb = *(const float4*)(ap + 4);
            bf16x8 v;
            v[0] = (short)f2bf(fa.x); v[1] = (short)f2bf(fa.y);
            v[2] = (short)f2bf(fa.z); v[3] = (short)f2bf(fa.w);
            v[4] = (short)f2bf(fb.x); v[5] = (short)f2bf(fb.y);
            v[6] = (short)f2bf(fb.z); v[7] = (short)f2bf(fb.w);
            af[kb] = v;
        }
        f32x4v a0 = {0.f,0.f,0.f,0.f}, a1 = {0.f,0.f,0.f,0.f};
        #pragma unroll
        for (int kb = 0; kb < 8; kb++){
            a0 = __builtin_amdgcn_mfma_f32_16x16x32_bf16(af[kb], bfr[0][kb], a0, 0, 0, 0);
            a1 = __builtin_amdgcn_mfma_f32_16x16x32_bf16(af[kb], bfr[1][kb], a1, 0, 0, 0);
        }
        #pragma unroll
        for (int r = 0; r < 4; r++){
            float p = silu_f(a0[r] + b1a) * w2a + silu_f(a1[r] + b1b) * w2b;
            #pragma unroll
            for (int m = 8; m >= 1; m >>= 1) p += __shfl_xor(p, m, 64);
            if (lm == 0) part[w][mt*16 + lq*4 + r] = p;
        }
    }
    __syncthreads();
    if (t < 48) part[0][t] = part[0][t] + part[1][t] + part[2][t] + part[3][t];
    __syncthreads();
    if (t < 8){
        float e[L_DIM]; float mx = -1e30f;
        #pragma unroll
        for (int l6 = 0; l6 < L_DIM; l6++) mx = fmaxf(mx, part[0][t*L_DIM + l6]);
        float s = 0.f;
        #pragma unroll
        for (int l6 = 0; l6 < L_DIM; l6++){ e[l6] = __expf(part[0][t*L_DIM + l6] - mx); s += e[l6]; }
        float inv = 1.f / s;
        #pragma unroll
        for (int l6 = 0; l6 < L_DIM; l6++) aw_l[t][l6] = e[l6] * inv;
    }
    __syncthreads();

    // ---- phase 2: weighted sums (wave handles 2 atoms) ----
    #pragma unroll
    for (int aa = 0; aa < 2; aa++){
        const int n = min(n0 + w*2 + aa, N - 1);
        float aw[L_DIM];
        #pragma unroll
        for (int l6 = 0; l6 < L_DIM; l6++) aw[l6] = aw_l[w*2 + aa][l6];

        const float* sp = s_stack + (size_t)n * (L_DIM * F_DIM) + l * 4;
        const float* vp = v_stack + (size_t)n * (L_DIM * 3 * F_DIM) + l * 4;
        float4 v0 = {0.f,0.f,0.f,0.f}, v1 = {0.f,0.f,0.f,0.f}, v2 = {0.f,0.f,0.f,0.f};
        float4 sj = {0.f,0.f,0.f,0.f};
        #pragma unroll
        for (int l6 = 0; l6 < L_DIM; l6++){
            const float a = aw[l6];
            float4 ss = *(const float4*)(sp + (size_t)l6 * F_DIM);
            float4 x0 = *(const float4*)(vp + (size_t)(l6*3+0) * F_DIM);
            float4 x1 = *(const float4*)(vp + (size_t)(l6*3+1) * F_DIM);
            float4 x2 = *(const float4*)(vp + (size_t)(l6*3+2) * F_DIM);
            v0.x = fmaf(a, x0.x, v0.x); v0.y = fmaf(a, x0.y, v0.y);
            v0.z = fmaf(a, x0.z, v0.z); v0.w = fmaf(a, x0.w, v0.w);
            v1.x = fmaf(a, x1.x, v1.x); v1.y = fmaf(a, x1.y, v1.y);
            v1.z = fmaf(a, x1.z, v1.z); v1.w = fmaf(a, x1.w, v1.w);
            v2.x = fmaf(a, x2.x, v2.x); v2.y = fmaf(a, x2.y, v2.y);
            v2.z = fmaf(a, x2.z, v2.z); v2.w = fmaf(a, x2.w, v2.w);
            sj.x = fmaf(a, ss.x, sj.x); sj.y = fmaf(a, ss.y, sj.y);
            sj.z = fmaf(a, ss.z, sj.z); sj.w = fmaf(a, ss.w, sj.w);
        }
        float4 ni;
        ni.x = sqrtf(v0.x*v0.x + v1.x*v1.x + v2.x*v2.x);
        ni.y = sqrtf(v0.y*v0.y + v1.y*v1.y + v2.y*v2.y);
        ni.z = sqrtf(v0.z*v0.z + v1.z*v1.z + v2.z*v2.z);
        ni.w = sqrtf(v0.w*v0.w + v1.w*v1.w + v2.w*v2.w);

        ushort4 o;
        o = (ushort4){f2bf(v0.x), f2bf(v0.y), f2bf(v0.z), f2bf(v0.w)};
        *(ushort4*)&VJKb[((size_t)n*3 + 0) * F_DIM + l*4] = o;
        o = (ushort4){f2bf(v1.x), f2bf(v1.y), f2bf(v1.z), f2bf(v1.w)};
        *(ushort4*)&VJKb[((size_t)n*3 + 1) * F_DIM + l*4] = o;
        o = (ushort4){f2bf(v2.x), f2bf(v2.y), f2bf(v2.z), f2bf(v2.w)};
        *(ushort4*)&VJKb[((size_t)n*3 + 2) * F_DIM + l*4] = o;
        o = (ushort4){f2bf(ni.x), f2bf(ni.y), f2bf(ni.z), f2bf(ni.w)};
        *(ushort4*)&NISb[(size_t)n * 512 + l*4] = o;
        o = (ushort4){f2bf(sj.x), f2bf(sj.y), f2bf(sj.z), f2bf(sj.w)};
        *(ushort4*)&NISb[(size_t)n * 512 + 256 + l*4] = o;
    }

    // ---- hist tail (merged kHist): 128 edges per block ----
    {
        int e = blockIdx.x * 128 + t;
        if (t < 128 && e < E) atomicAdd(&cnt[pe[(size_t)e*2]], 1);
    }
}

// ---------------- kA2: U (blk<gU) / T (blk<gUT) / scatter tail (blk>=gUT) ----------------
__global__ __launch_bounds__(256) void kA2(
    const unsigned short* __restrict__ VJKb, const unsigned short* __restrict__ w1bt,
    const unsigned short* __restrict__ NISb, const unsigned short* __restrict__ w1cdt,
    const float* __restrict__ msg_b1, float* __restrict__ UT4,
    const int* __restrict__ pe, const int* __restrict__ offs,
    int* __restrict__ pos, int* __restrict__ perm, int E,
    int gU, int gUT)
{
    const int t  = threadIdx.x;
    const int l  = t & 63;
    const int w  = t >> 6;
    const int lm = l & 15, lq = l >> 4;

    if ((int)blockIdx.x >= gUT){
        // ---- scatter tail (merged kScatter) ----
        int e = (blockIdx.x - gUT) * 256 + t;
        if (e < E){
            int i = pe[(size_t)e*2];
            int slot = atomicAdd(&pos[i], 1);
            perm[offs[i] + slot] = e;
        }
        return;
    }

    if ((int)blockIdx.x < gU){
        bf16x8 bfr[4][8];
        #pragma unroll
        for (int ct = 0; ct < 4; ct++)
            #pragma unroll
            for (int kb = 0; kb < 8; kb++)
                bfr[ct][kb] = *(const bf16x8*)(w1bt + (size_t)(w*64 + ct*16 + lm) * 256 + kb*32 + lq*8);

        const int r00 = blockIdx.x * 128;
        #pragma unroll 1
        for (int mt = 0; mt < 8; mt++){
            const int r0 = r00 + mt * 16;
            bf16x8 af[8];
            #pragma unroll
            for (int kb = 0; kb < 8; kb++)
                af[kb] = *(const bf16x8*)(VJKb + (size_t)(r0 + lm) * 256 + kb*32 + lq*8);
            f32x4v acc[4];
            #pragma unroll
            for (int ct = 0; ct < 4; ct++) acc[ct] = (f32x4v){0.f,0.f,0.f,0.f};
            #pragma unroll
            for (int kb = 0; kb < 8; kb++)
                #pragma unroll
                for (int ct = 0; ct < 4; ct++)
                    acc[ct] = __builtin_amdgcn_mfma_f32_16x16x32_bf16(af[kb], bfr[ct][kb], acc[ct], 0, 0, 0);
            #pragma unroll
            for (int ct = 0; ct < 4; ct++){
                const int col = w*64 + ct*16 + lm;
                #pragma unroll
                for (int r = 0; r < 4; r++){
                    const int row = r0 + lq*4 + r;
                    const int n = row / 3, c = row - n*3;
                    UT4[(((size_t)n << 8) + col) * 4 + c] = acc[ct][r];
                }
            }
        }
    } else {
        const int bid = blockIdx.x - gU;
        const int ch = bid & 1;
        const int bm = bid >> 1;

        bf16x8 bfr[2][16];
        #pragma unroll
        for (int ct = 0; ct < 2; ct++)
            #pragma unroll
            for (int kb = 0; kb < 16; kb++)
                bfr[ct][kb] = *(const bf16x8*)(w1cdt + (size_t)(ch*128 + w*32 + ct*16 + lm) * 512 + kb*32 + lq*8);

        const int r00 = bm * 128;
        #pragma unroll 1
        for (int mt = 0; mt < 8; mt++){
            const int r0 = r00 + mt * 16;
            bf16x8 af[16];
            #pragma unroll
            for (int kb = 0; kb < 16; kb++)
                af[kb] = *(const bf16x8*)(NISb + (size_t)(r0 + lm) * 512 + kb*32 + lq*8);
            f32x4v acc[2];
            #pragma unroll
            for (int ct = 0; ct < 2; ct++) acc[ct] = (f32x4v){0.f,0.f,0.f,0.f};
            #pragma unroll
            for (int kb = 0; kb < 16; kb++)
                #pragma unroll
                for (int ct = 0; ct < 2; ct++)
                    acc[ct] = __builtin_amdgcn_mfma_f32_16x16x32_bf16(af[kb], bfr[ct][kb], acc[ct], 0, 0, 0);
            #pragma unroll
            for (int ct = 0; ct < 2; ct++){
                const int col = ch*128 + w*32 + ct*16 + lm;
                const float bias = msg_b1[col];
                #pragma unroll
                for (int r = 0; r < 4; r++){
                    const int n = r0 + lq*4 + r;
                    UT4[(((size_t)n << 8) + col) * 4 + 3] = acc[ct][r] + bias;
                }
            }
        }
    }
}

// ---------------- kScan ----------------
__global__ __launch_bounds__(1024) void kScan(const int* __restrict__ cnt, int* __restrict__ off, int N){
    __shared__ int sums[1024];
    const int t = threadIdx.x;
    const int base = t * 8;
    int c[8]; int s = 0;
    #pragma unroll
    for (int j = 0; j < 8; j++){
        int v = (base + j < N) ? cnt[base + j] : 0;
        c[j] = s; s += v;
    }
    sums[t] = s;
    __syncthreads();
    for (int d = 1; d < 1024; d <<= 1){
        int v = (t >= d) ? sums[t - d] : 0;
        __syncthreads();
        sums[t] += v;
        __syncthreads();
    }
    int excl = (t == 0) ? 0 : sums[t - 1];
    #pragma unroll
    for (int j = 0; j < 8; j++)
        if (base + j < N) off[base + j] = excl + c[j];
    if (t == 1023) off[N] = sums[1023];
}

// ---------------- kB1: fused geometry + edge MLP + scatter (r12 occupancy push) ----------------
// W2 fragments re-read from L2 (no register cache); per-mt sequential MFMA1/pairs;
// __launch_bounds__(256,6) targets 6 blocks/CU (VGPR <= 85).
__global__ __launch_bounds__(256, 6) void kB1(
    const int* __restrict__ pe, const float* __restrict__ disp,
    const float* __restrict__ cell,
    const float* __restrict__ atom_xyz, const float* __restrict__ probe_xyz,
    const float* __restrict__ UT4,
    const float* __restrict__ msg_w1,
    const unsigned short* __restrict__ w2t, const float* __restrict__ msg_b2,
    const float* __restrict__ msg_w3, const float* __restrict__ msg_b3,
    const int* __restrict__ perm,
    float* __restrict__ rho, int E)
{
    __shared__ unsigned short x_lds[32 * 256];   // 16 KB, XOR-swizzled
    __shared__ unsigned short epi_b[32 * 40];    // 2.5 KB
    __shared__ int   ai_l[32];
    __shared__ int   pp_l[32];
    __shared__ float4 rc4_l[32];
    __shared__ float part[4][32];

    char* xbase = (char*)x_lds;

    const int t  = threadIdx.x;
    const int l  = t & 63;
    const int w  = t >> 6;
    const int lq = l >> 4;
    const int lm = l & 15;

    const float c0 = cell[0], c1 = cell[1], c2 = cell[2];
    const float c3 = cell[3], c4 = cell[4], c5 = cell[5];
    const float c6 = cell[6], c7 = cell[7], c8 = cell[8];

    bf16x8 w1afr[4];
    #pragma unroll
    for (int nt = 0; nt < 4; nt++){
        const int col = w*64 + nt*16 + lm;
        bf16x8 v;
        #pragma unroll
        for (int j = 0; j < 8; j++)
            v[j] = (short)f2bf(msg_w1[(size_t)(lq*8 + j) * F_DIM + col]);
        w1afr[nt] = v;
    }

    const float b2v0 = msg_b2[w*32 + lm];
    const float b2v1 = msg_b2[w*32 + 16 + lm];
    const float w3v0 = msg_w3[w*32 + lm];
    const float w3v1 = msg_w3[w*32 + 16 + lm];
    const float b3   = msg_b3[0];

    // W2 fragment base pointers (loads issued per-use inside MFMA2; L2-hot)
    const unsigned short* w2p0 = w2t + (size_t)(w*32 + lm)      * F_DIM + lq*8;
    const unsigned short* w2p1 = w2t + (size_t)(w*32 + 16 + lm) * F_DIM + lq*8;

    const int e0 = blockIdx.x * 128;

    int ee_r[4], ia_r[4], ip_r[4];
    #pragma unroll
    for (int bb = 0; bb < 4; bb++){
        int s = min(e0 + bb*32 + (t >> 3), E - 1);
        ee_r[bb] = perm[s];
    }
    #pragma unroll
    for (int bb = 0; bb < 4; bb++){
        ia_r[bb] = pe[(size_t)ee_r[bb]*2];
        ip_r[bb] = pe[(size_t)ee_r[bb]*2 + 1];
    }

    #pragma unroll 1
    for (int bb = 0; bb < 4; bb++){
        const int e0b = e0 + bb * 32;

        {
            const int slot = t >> 3, q = t & 7;
            const int ee = ee_r[bb];
            const int ia = ia_r[bb];
            const int ip = ip_r[bb];
            const float d0 = disp[(size_t)ee*3], d1 = disp[(size_t)ee*3+1], d2 = disp[(size_t)ee*3+2];
            const float sx = d0*c0 + d1*c3 + d2*c6;
            const float sy = d0*c1 + d1*c4 + d2*c7;
            const float sz = d0*c2 + d1*c5 + d2*c8;
            const float dx = probe_xyz[(size_t)ip*3+0] - (atom_xyz[(size_t)ia*3+0] + sx);
            const float dy = probe_xyz[(size_t)ip*3+1] - (atom_xyz[(size_t)ia*3+1] + sy);
            const float dz = probe_xyz[(size_t)ip*3+2] - (atom_xyz[(size_t)ia*3+2] + sz);
            const float dist = sqrtf(dx*dx + dy*dy + dz*dz);
            const float inv  = 1.f / (dist + 1e-8f);
            const float base = dist * (PI_F / CUTOFF_F);
            ushort4 eb;
            eb.x = f2bf(__sinf(base * (float)(q*4 + 1)) * inv);
            eb.y = f2bf(__sinf(base * (float)(q*4 + 2)) * inv);
            eb.z = f2bf(__sinf(base * (float)(q*4 + 3)) * inv);
            eb.w = f2bf(__sinf(base * (float)(q*4 + 4)) * inv);
            *(ushort4*)&epi_b[slot*40 + q*4] = eb;
            if (q == 0){
                ai_l[slot] = ia;
                pp_l[slot] = ip;
                float cw = (dist < CUTOFF_F) ? 0.5f * (__cosf(base) + 1.f) : 0.f;
                rc4_l[slot] = (float4){dx*inv, dy*inv, dz*inv, cw};
            }
        }
        __syncthreads();

        // ---- MFMA1 + pairs, per-mt sequential (halves pacc live range) ----
        #pragma unroll
        for (int mt = 0; mt < 2; mt++){
            f32x4v pacc[4];
            #pragma unroll
            for (int nt = 0; nt < 4; nt++) pacc[nt] = (f32x4v){0.f,0.f,0.f,0.f};
            const bf16x8 af = *(const bf16x8*)&epi_b[(mt*16 + lm)*40 + lq*8];
            #pragma unroll
            for (int nt = 0; nt < 4; nt++)
                pacc[nt] = __builtin_amdgcn_mfma_f32_16x16x32_bf16(af, w1afr[nt], pacc[nt], 0, 0, 0);

            #pragma unroll
            for (int r = 0; r < 4; r++){
                const int e = mt*16 + lq*4 + r;
                const int i = ai_l[e];
                const float4 rc = rc4_l[e];
                const float* up = UT4 + ((size_t)i << 10);
                #pragma unroll
                for (int nt = 0; nt < 4; nt++){
                    const int col = w*64 + nt*16 + lm;
                    const float4 ut = *(const float4*)(up + (size_t)col * 4);
                    float z = pacc[nt][r] + ut.w;
                    z = fmaf(rc.x, ut.x, fmaf(rc.y, ut.y, fmaf(rc.z, ut.z, z)));
                    const int wofs = e*512 + ((col*2) ^ ((e & 7) << 4));
                    *(unsigned short*)(xbase + wofs) = f2bf(silu_f(z));
                }
            }
        }
        __syncthreads();

        // ---- MFMA2: B-fragments streamed from L2 (no register cache) ----
        f32x4v acc00 = {0.f,0.f,0.f,0.f}, acc01 = {0.f,0.f,0.f,0.f};
        f32x4v acc10 = {0.f,0.f,0.f,0.f}, acc11 = {0.f,0.f,0.f,0.f};
        const int eA0 = lm;
        const int eA1 = 16 + lm;
        #pragma unroll
        for (int kb = 0; kb < 8; kb++){
            const int ko = kb*64 + lq*16;
            bf16x8 b0 = *(const bf16x8*)(w2p0 + kb*32);
            bf16x8 b1 = *(const bf16x8*)(w2p1 + kb*32);
            bf16x8 af0 = *(const bf16x8*)(xbase + eA0*512 + (ko ^ ((eA0 & 7) << 4)));
            bf16x8 af1 = *(const bf16x8*)(xbase + eA1*512 + (ko ^ ((eA1 & 7) << 4)));
            acc00 = __builtin_amdgcn_mfma_f32_16x16x32_bf16(af0, b0, acc00, 0, 0, 0);
            acc01 = __builtin_amdgcn_mfma_f32_16x16x32_bf16(af0, b1, acc01, 0, 0, 0);
            acc10 = __builtin_amdgcn_mfma_f32_16x16x32_bf16(af1, b0, acc10, 0, 0, 0);
            acc11 = __builtin_amdgcn_mfma_f32_16x16x32_bf16(af1, b1, acc11, 0, 0, 0);
        }

        float pr0[4], pr1[4];
        #pragma unroll
        for (int r = 0; r < 4; r++){
            pr0[r] = silu_f(acc00[r] + b2v0) * w3v0 + silu_f(acc01[r] + b2v1) * w3v1;
            pr1[r] = silu_f(acc10[r] + b2v0) * w3v0 + silu_f(acc11[r] + b2v1) * w3v1;
        }
        #pragma unroll
        for (int r = 0; r < 4; r++){
            #pragma unroll
            for (int m = 8; m >= 1; m >>= 1){
                pr0[r] += __shfl_xor(pr0[r], m, 64);
                pr1[r] += __shfl_xor(pr1[r], m, 64);
            }
        }
        if (lm == 0){
            #pragma unroll
            for (int r = 0; r < 4; r++){
                part[w][lq*4 + r]      = pr0[r];
                part[w][16 + lq*4 + r] = pr1[r];
            }
        }
        __syncthreads();

        if (t < 32 && (e0b + t) < E){
            float tot = part[0][t] + part[1][t] + part[2][t] + part[3][t] + b3;
            atomicAdd(&rho[pp_l[t]], tot * rc4_l[t].w);
        }
        __syncthreads();
    }
}

extern "C" void kernel_launch(void* const* d_in, const int* in_sizes, int n_in,
                              void* d_out, int out_size, void* d_ws, size_t ws_size,
                              hipStream_t stream)
{
    const float* s_stack   = (const float*)d_in[0];
    const float* v_stack   = (const float*)d_in[1];
    const float* atom_xyz  = (const float*)d_in[2];
    const float* probe_xyz = (const float*)d_in[3];
    const float* cell      = (const float*)d_in[4];
    const float* disp      = (const float*)d_in[5];
    const float* attn_w1   = (const float*)d_in[6];
    const float* attn_b1   = (const float*)d_in[7];
    const float* attn_w2   = (const float*)d_in[8];
    const float* msg_w1    = (const float*)d_in[10];
    const float* msg_b1    = (const float*)d_in[11];
    const float* msg_w2    = (const float*)d_in[12];
    const float* msg_b2    = (const float*)d_in[13];
    const float* msg_w3    = (const float*)d_in[14];
    const float* msg_b3    = (const float*)d_in[15];
    const int*   pe        = (const int*)d_in[16];

    const int N = in_sizes[0] / (L_DIM * F_DIM);
    const int E = in_sizes[16] / 2;
    const int P = out_size;
    const size_t NF = (size_t)N * F_DIM;

    float* ws = (float*)d_ws;
    unsigned short* VJKb = (unsigned short*)ws;            // 3N x 256 bf16
    unsigned short* NISb = VJKb + 3*NF;                    // N x 512 bf16
    float* UT4 = ws + (5*NF)/2;                            // N x 256 x 4 f32
    unsigned short* w1bt  = (unsigned short*)(ws + (13*NF)/2);
    unsigned short* w1cdt = w1bt + 65536;
    unsigned short* w2t   = w1cdt + 131072;
    unsigned short* wA1t  = w2t + 32768;
    int* cnt  = (int*)(wA1t + 32768);
    int* pos  = cnt + N;
    int* offs = pos + N;
    int* perm = offs + N + 1;

    const int prepElems = 262144 + 32768 + 2 * N;
    kPrep<<<(prepElems + 255) / 256, 256, 0, stream>>>(
        msg_w1, msg_w2, attn_w1, w1bt, w1cdt, w2t, wA1t,
        (float*)d_out, P, cnt, 2 * N);

    // kAW includes the hist tail (cnt zeroed by kPrep)
    kAW<<<(N + 7) / 8, 256, 0, stream>>>(s_stack, v_stack, wA1t, attn_b1, attn_w2,
                                         VJKb, NISb, pe, cnt, E, N);

    kScan<<<1, 1024, 0, stream>>>(cnt, offs, N);

    // kA2 includes the scatter tail (needs offs from kScan)
    const int gU  = (3 * N) / 128;                         // 192
    const int gT  = (N / 128) * 2;                         // 128
    const int gUT = gU + gT;
    const int gS  = (E + 255) / 256;                       // 512
    kA2<<<gUT + gS, 256, 0, stream>>>(VJKb, w1bt, NISb, w1cdt, msg_b1, UT4,
                                      pe, offs, pos, perm, E, gU, gUT);

    kB1<<<(E + 127) / 128, 256, 0, stream>>>(pe, disp, cell, atom_xyz, probe_xyz,
                                             UT4, msg_w1,
                                             w2t, msg_b2, msg_w3, msg_b3,
                                             perm, (float*)d_out, E);
}

// Round 13
// 176.097 us; speedup vs baseline: 1.7769x; 1.7769x over previous
//
#include <hip/hip_runtime.h>
#include <math.h>
#include <stdint.h>

// PaiNN QM encoder, round 13.
//   U = V_JK @ W1b  (N,3,256)   T = b1 + n_i@W1c + S_JK@W1d  (N,256)
//   per edge: x = silu(T[i] + e_pi@W1a + r_hat.U[i]); m = (silu(x@W2+b2))@w3+b3
// r13: kB1 reverted to the r11 version (VGPR~120, W2 register-cached,
// plain launch_bounds -- r12's (256,6) cap caused 160MB of scratch spill,
// VGPR 40, 2.3x slower). Kept from r12: kHist merged into kAW tail and
// kScatter merged into kA2 tail (both correctness-validated in r12).

#define L_DIM 6
#define F_DIM 256
#define FH_DIM 128
#define DRBF 32
#define CUTOFF_F 4.0f
#define PI_F 3.14159265358979323846f

using bf16x8 = __attribute__((ext_vector_type(8))) short;
using f32x4v = __attribute__((ext_vector_type(4))) float;

__device__ __forceinline__ float silu_f(float x){ return x / (1.f + __expf(-x)); }

__device__ __forceinline__ unsigned short f2bf(float f){
    uint32_t u = __float_as_uint(f);
    uint32_t r = (u + 0x7fffu + ((u >> 16) & 1u)) >> 16;   // RNE
    return (unsigned short)r;
}

// ---------------- kPrep: weight transpose/convert + output/CSR zeroing ----------------
__global__ __launch_bounds__(256) void kPrep(
    const float* __restrict__ msg_w1, const float* __restrict__ msg_w2,
    const float* __restrict__ attn_w1,
    unsigned short* __restrict__ w1bt, unsigned short* __restrict__ w1cdt,
    unsigned short* __restrict__ w2t, unsigned short* __restrict__ wA1t,
    float* __restrict__ rho, int P, int* __restrict__ cntpos, int CN)
{
    int idx = blockIdx.x * 256 + threadIdx.x;
    if (idx < 65536){
        int k = idx >> 8, j = idx & 255;
        w1bt[(size_t)j * 256 + k] = f2bf(msg_w1[(size_t)(DRBF + k) * F_DIM + j]);
    } else if (idx < 196608){
        int i2 = idx - 65536;
        int k = i2 >> 8, j = i2 & 255;
        w1cdt[(size_t)j * 512 + k] = f2bf(msg_w1[(size_t)(DRBF + 256 + k) * F_DIM + j]);
    } else if (idx < 229376){
        int i3 = idx - 196608;
        int k = i3 >> 7, h = i3 & 127;
        w2t[(size_t)h * 256 + k] = f2bf(msg_w2[(size_t)k * FH_DIM + h]);
    } else if (idx < 262144){
        int i4 = idx - 229376;
        int j = i4 >> 8, k = i4 & 255;
        wA1t[(size_t)j * 256 + k] = f2bf(attn_w1[(size_t)k * FH_DIM + j]);
    } else if (idx < 262144 + 32768){
        int i5 = idx - 262144;
        if (i5 < P) rho[i5] = 0.f;
    } else {
        int i6 = idx - 262144 - 32768;
        if (i6 < CN) cntpos[i6] = 0;
    }
}

// ---------------- kAW: fused attention + hist tail (validated r11/r12) ----------------
__global__ __launch_bounds__(256) void kAW(
    const float* __restrict__ s_stack, const float* __restrict__ v_stack,
    const unsigned short* __restrict__ wA1t,
    const float* __restrict__ attn_b1, const float* __restrict__ attn_w2,
    unsigned short* __restrict__ VJKb, unsigned short* __restrict__ NISb,
    const int* __restrict__ pe, int* __restrict__ cnt, int E, int N)
{
    __shared__ float part[4][48];
    __shared__ float aw_l[8][8];

    const int t  = threadIdx.x;
    const int l  = t & 63;
    const int w  = t >> 6;
    const int lm = l & 15, lq = l >> 4;

    bf16x8 bfr[2][8];
    #pragma unroll
    for (int nt2 = 0; nt2 < 2; nt2++){
        const int col = w*32 + nt2*16 + lm;
        #pragma unroll
        for (int kb = 0; kb < 8; kb++)
            bfr[nt2][kb] = *(const bf16x8*)(wA1t + (size_t)col * 256 + kb*32 + lq*8);
    }
    const float b1a = attn_b1[w*32 + lm];
    const float b1b = attn_b1[w*32 + 16 + lm];
    const float w2a = attn_w2[w*32 + lm];
    const float w2b = attn_w2[w*32 + 16 + lm];

    const int n0 = blockIdx.x * 8;
    const size_t rbase = (size_t)n0 * L_DIM;
    const size_t rmax  = (size_t)N * L_DIM - 1;

    // ---- phase 1: logits (48 rows = 3 m-tiles) ----
    #pragma unroll
    for (int mt = 0; mt < 3; mt++){
        const size_t r0 = rbase + mt * 16;
        bf16x8 af[8];
        #pragma unroll
        for (int kb = 0; kb < 8; kb++){
            size_t row = r0 + lm; if (row > rmax) row = rmax;
            const float* ap = s_stack + row * 256 + kb*32 + lq*8;
            float4 fa = *(const float4*)ap;
            float4 fb = *(const float4*)(ap + 4);
            bf16x8 v;
            v[0] = (short)f2bf(fa.x); v[1] = (short)f2bf(fa.y);
            v[2] = (short)f2bf(fa.z); v[3] = (short)f2bf(fa.w);
            v[4] = (short)f2bf(fb.x); v[5] = (short)f2bf(fb.y);
            v[6] = (short)f2bf(fb.z); v[7] = (short)f2bf(fb.w);
            af[kb] = v;
        }
        f32x4v a0 = {0.f,0.f,0.f,0.f}, a1 = {0.f,0.f,0.f,0.f};
        #pragma unroll
        for (int kb = 0; kb < 8; kb++){
            a0 = __builtin_amdgcn_mfma_f32_16x16x32_bf16(af[kb], bfr[0][kb], a0, 0, 0, 0);
            a1 = __builtin_amdgcn_mfma_f32_16x16x32_bf16(af[kb], bfr[1][kb], a1, 0, 0, 0);
        }
        #pragma unroll
        for (int r = 0; r < 4; r++){
            float p = silu_f(a0[r] + b1a) * w2a + silu_f(a1[r] + b1b) * w2b;
            #pragma unroll
            for (int m = 8; m >= 1; m >>= 1) p += __shfl_xor(p, m, 64);
            if (lm == 0) part[w][mt*16 + lq*4 + r] = p;
        }
    }
    __syncthreads();
    if (t < 48) part[0][t] = part[0][t] + part[1][t] + part[2][t] + part[3][t];
    __syncthreads();
    if (t < 8){
        float e[L_DIM]; float mx = -1e30f;
        #pragma unroll
        for (int l6 = 0; l6 < L_DIM; l6++) mx = fmaxf(mx, part[0][t*L_DIM + l6]);
        float s = 0.f;
        #pragma unroll
        for (int l6 = 0; l6 < L_DIM; l6++){ e[l6] = __expf(part[0][t*L_DIM + l6] - mx); s += e[l6]; }
        float inv = 1.f / s;
        #pragma unroll
        for (int l6 = 0; l6 < L_DIM; l6++) aw_l[t][l6] = e[l6] * inv;
    }
    __syncthreads();

    // ---- phase 2: weighted sums (wave handles 2 atoms) ----
    #pragma unroll
    for (int aa = 0; aa < 2; aa++){
        const int n = min(n0 + w*2 + aa, N - 1);
        float aw[L_DIM];
        #pragma unroll
        for (int l6 = 0; l6 < L_DIM; l6++) aw[l6] = aw_l[w*2 + aa][l6];

        const float* sp = s_stack + (size_t)n * (L_DIM * F_DIM) + l * 4;
        const float* vp = v_stack + (size_t)n * (L_DIM * 3 * F_DIM) + l * 4;
        float4 v0 = {0.f,0.f,0.f,0.f}, v1 = {0.f,0.f,0.f,0.f}, v2 = {0.f,0.f,0.f,0.f};
        float4 sj = {0.f,0.f,0.f,0.f};
        #pragma unroll
        for (int l6 = 0; l6 < L_DIM; l6++){
            const float a = aw[l6];
            float4 ss = *(const float4*)(sp + (size_t)l6 * F_DIM);
            float4 x0 = *(const float4*)(vp + (size_t)(l6*3+0) * F_DIM);
            float4 x1 = *(const float4*)(vp + (size_t)(l6*3+1) * F_DIM);
            float4 x2 = *(const float4*)(vp + (size_t)(l6*3+2) * F_DIM);
            v0.x = fmaf(a, x0.x, v0.x); v0.y = fmaf(a, x0.y, v0.y);
            v0.z = fmaf(a, x0.z, v0.z); v0.w = fmaf(a, x0.w, v0.w);
            v1.x = fmaf(a, x1.x, v1.x); v1.y = fmaf(a, x1.y, v1.y);
            v1.z = fmaf(a, x1.z, v1.z); v1.w = fmaf(a, x1.w, v1.w);
            v2.x = fmaf(a, x2.x, v2.x); v2.y = fmaf(a, x2.y, v2.y);
            v2.z = fmaf(a, x2.z, v2.z); v2.w = fmaf(a, x2.w, v2.w);
            sj.x = fmaf(a, ss.x, sj.x); sj.y = fmaf(a, ss.y, sj.y);
            sj.z = fmaf(a, ss.z, sj.z); sj.w = fmaf(a, ss.w, sj.w);
        }
        float4 ni;
        ni.x = sqrtf(v0.x*v0.x + v1.x*v1.x + v2.x*v2.x);
        ni.y = sqrtf(v0.y*v0.y + v1.y*v1.y + v2.y*v2.y);
        ni.z = sqrtf(v0.z*v0.z + v1.z*v1.z + v2.z*v2.z);
        ni.w = sqrtf(v0.w*v0.w + v1.w*v1.w + v2.w*v2.w);

        ushort4 o;
        o = (ushort4){f2bf(v0.x), f2bf(v0.y), f2bf(v0.z), f2bf(v0.w)};
        *(ushort4*)&VJKb[((size_t)n*3 + 0) * F_DIM + l*4] = o;
        o = (ushort4){f2bf(v1.x), f2bf(v1.y), f2bf(v1.z), f2bf(v1.w)};
        *(ushort4*)&VJKb[((size_t)n*3 + 1) * F_DIM + l*4] = o;
        o = (ushort4){f2bf(v2.x), f2bf(v2.y), f2bf(v2.z), f2bf(v2.w)};
        *(ushort4*)&VJKb[((size_t)n*3 + 2) * F_DIM + l*4] = o;
        o = (ushort4){f2bf(ni.x), f2bf(ni.y), f2bf(ni.z), f2bf(ni.w)};
        *(ushort4*)&NISb[(size_t)n * 512 + l*4] = o;
        o = (ushort4){f2bf(sj.x), f2bf(sj.y), f2bf(sj.z), f2bf(sj.w)};
        *(ushort4*)&NISb[(size_t)n * 512 + 256 + l*4] = o;
    }

    // ---- hist tail (merged kHist): 128 edges per block ----
    {
        int e = blockIdx.x * 128 + t;
        if (t < 128 && e < E) atomicAdd(&cnt[pe[(size_t)e*2]], 1);
    }
}

// ---------------- kA2: U (blk<gU) / T (blk<gUT) / scatter tail (blk>=gUT) ----------------
__global__ __launch_bounds__(256) void kA2(
    const unsigned short* __restrict__ VJKb, const unsigned short* __restrict__ w1bt,
    const unsigned short* __restrict__ NISb, const unsigned short* __restrict__ w1cdt,
    const float* __restrict__ msg_b1, float* __restrict__ UT4,
    const int* __restrict__ pe, const int* __restrict__ offs,
    int* __restrict__ pos, int* __restrict__ perm, int E,
    int gU, int gUT)
{
    const int t  = threadIdx.x;
    const int l  = t & 63;
    const int w  = t >> 6;
    const int lm = l & 15, lq = l >> 4;

    if ((int)blockIdx.x >= gUT){
        // ---- scatter tail (merged kScatter) ----
        int e = (blockIdx.x - gUT) * 256 + t;
        if (e < E){
            int i = pe[(size_t)e*2];
            int slot = atomicAdd(&pos[i], 1);
            perm[offs[i] + slot] = e;
        }
        return;
    }

    if ((int)blockIdx.x < gU){
        bf16x8 bfr[4][8];
        #pragma unroll
        for (int ct = 0; ct < 4; ct++)
            #pragma unroll
            for (int kb = 0; kb < 8; kb++)
                bfr[ct][kb] = *(const bf16x8*)(w1bt + (size_t)(w*64 + ct*16 + lm) * 256 + kb*32 + lq*8);

        const int r00 = blockIdx.x * 128;
        #pragma unroll 1
        for (int mt = 0; mt < 8; mt++){
            const int r0 = r00 + mt * 16;
            bf16x8 af[8];
            #pragma unroll
            for (int kb = 0; kb < 8; kb++)
                af[kb] = *(const bf16x8*)(VJKb + (size_t)(r0 + lm) * 256 + kb*32 + lq*8);
            f32x4v acc[4];
            #pragma unroll
            for (int ct = 0; ct < 4; ct++) acc[ct] = (f32x4v){0.f,0.f,0.f,0.f};
            #pragma unroll
            for (int kb = 0; kb < 8; kb++)
                #pragma unroll
                for (int ct = 0; ct < 4; ct++)
                    acc[ct] = __builtin_amdgcn_mfma_f32_16x16x32_bf16(af[kb], bfr[ct][kb], acc[ct], 0, 0, 0);
            #pragma unroll
            for (int ct = 0; ct < 4; ct++){
                const int col = w*64 + ct*16 + lm;
                #pragma unroll
                for (int r = 0; r < 4; r++){
                    const int row = r0 + lq*4 + r;
                    const int n = row / 3, c = row - n*3;
                    UT4[(((size_t)n << 8) + col) * 4 + c] = acc[ct][r];
                }
            }
        }
    } else {
        const int bid = blockIdx.x - gU;
        const int ch = bid & 1;
        const int bm = bid >> 1;

        bf16x8 bfr[2][16];
        #pragma unroll
        for (int ct = 0; ct < 2; ct++)
            #pragma unroll
            for (int kb = 0; kb < 16; kb++)
                bfr[ct][kb] = *(const bf16x8*)(w1cdt + (size_t)(ch*128 + w*32 + ct*16 + lm) * 512 + kb*32 + lq*8);

        const int r00 = bm * 128;
        #pragma unroll 1
        for (int mt = 0; mt < 8; mt++){
            const int r0 = r00 + mt * 16;
            bf16x8 af[16];
            #pragma unroll
            for (int kb = 0; kb < 16; kb++)
                af[kb] = *(const bf16x8*)(NISb + (size_t)(r0 + lm) * 512 + kb*32 + lq*8);
            f32x4v acc[2];
            #pragma unroll
            for (int ct = 0; ct < 2; ct++) acc[ct] = (f32x4v){0.f,0.f,0.f,0.f};
            #pragma unroll
            for (int kb = 0; kb < 16; kb++)
                #pragma unroll
                for (int ct = 0; ct < 2; ct++)
                    acc[ct] = __builtin_amdgcn_mfma_f32_16x16x32_bf16(af[kb], bfr[ct][kb], acc[ct], 0, 0, 0);
            #pragma unroll
            for (int ct = 0; ct < 2; ct++){
                const int col = ch*128 + w*32 + ct*16 + lm;
                const float bias = msg_b1[col];
                #pragma unroll
                for (int r = 0; r < 4; r++){
                    const int n = r0 + lq*4 + r;
                    UT4[(((size_t)n << 8) + col) * 4 + 3] = acc[ct][r] + bias;
                }
            }
        }
    }
}

// ---------------- kScan ----------------
__global__ __launch_bounds__(1024) void kScan(const int* __restrict__ cnt, int* __restrict__ off, int N){
    __shared__ int sums[1024];
    const int t = threadIdx.x;
    const int base = t * 8;
    int c[8]; int s = 0;
    #pragma unroll
    for (int j = 0; j < 8; j++){
        int v = (base + j < N) ? cnt[base + j] : 0;
        c[j] = s; s += v;
    }
    sums[t] = s;
    __syncthreads();
    for (int d = 1; d < 1024; d <<= 1){
        int v = (t >= d) ? sums[t - d] : 0;
        __syncthreads();
        sums[t] += v;
        __syncthreads();
    }
    int excl = (t == 0) ? 0 : sums[t - 1];
    #pragma unroll
    for (int j = 0; j < 8; j++)
        if (base + j < N) off[base + j] = excl + c[j];
    if (t == 1023) off[N] = sums[1023];
}

// ---------------- kB1: fused geometry + edge MLP + scatter (r11 version, measured ~84us) ----------------
__global__ __launch_bounds__(256) void kB1(
    const int* __restrict__ pe, const float* __restrict__ disp,
    const float* __restrict__ cell,
    const float* __restrict__ atom_xyz, const float* __restrict__ probe_xyz,
    const float* __restrict__ UT4,
    const float* __restrict__ msg_w1,
    const unsigned short* __restrict__ w2t, const float* __restrict__ msg_b2,
    const float* __restrict__ msg_w3, const float* __restrict__ msg_b3,
    const int* __restrict__ perm,
    float* __restrict__ rho, int E)
{
    __shared__ unsigned short x_lds[32 * 256];   // 16 KB, XOR-swizzled
    __shared__ unsigned short epi_b[32 * 40];    // 2.5 KB
    __shared__ int   ai_l[32];
    __shared__ int   pp_l[32];
    __shared__ float4 rc4_l[32];
    __shared__ float part[4][32];

    char* xbase = (char*)x_lds;

    const int t  = threadIdx.x;
    const int l  = t & 63;
    const int w  = t >> 6;
    const int lq = l >> 4;
    const int lm = l & 15;

    const float c0 = cell[0], c1 = cell[1], c2 = cell[2];
    const float c3 = cell[3], c4 = cell[4], c5 = cell[5];
    const float c6 = cell[6], c7 = cell[7], c8 = cell[8];

    bf16x8 w1afr[4];
    #pragma unroll
    for (int nt = 0; nt < 4; nt++){
        const int col = w*64 + nt*16 + lm;
        bf16x8 v;
        #pragma unroll
        for (int j = 0; j < 8; j++)
            v[j] = (short)f2bf(msg_w1[(size_t)(lq*8 + j) * F_DIM + col]);
        w1afr[nt] = v;
    }

    bf16x8 bfr[2][8];
    #pragma unroll
    for (int nt2 = 0; nt2 < 2; nt2++){
        const int h = w*32 + nt2*16 + lm;
        #pragma unroll
        for (int kb = 0; kb < 8; kb++)
            bfr[nt2][kb] = *(const bf16x8*)(w2t + (size_t)h * F_DIM + kb*32 + lq*8);
    }
    const float b2v0 = msg_b2[w*32 + lm];
    const float b2v1 = msg_b2[w*32 + 16 + lm];
    const float w3v0 = msg_w3[w*32 + lm];
    const float w3v1 = msg_w3[w*32 + 16 + lm];
    const float b3   = msg_b3[0];

    const int e0 = blockIdx.x * 128;

    int ee_r[4], ia_r[4], ip_r[4];
    #pragma unroll
    for (int bb = 0; bb < 4; bb++){
        int s = min(e0 + bb*32 + (t >> 3), E - 1);
        ee_r[bb] = perm[s];
    }
    #pragma unroll
    for (int bb = 0; bb < 4; bb++){
        ia_r[bb] = pe[(size_t)ee_r[bb]*2];
        ip_r[bb] = pe[(size_t)ee_r[bb]*2 + 1];
    }

    #pragma unroll 1
    for (int bb = 0; bb < 4; bb++){
        const int e0b = e0 + bb * 32;

        {
            const int slot = t >> 3, q = t & 7;
            const int ee = ee_r[bb];
            const int ia = ia_r[bb];
            const int ip = ip_r[bb];
            const float d0 = disp[(size_t)ee*3], d1 = disp[(size_t)ee*3+1], d2 = disp[(size_t)ee*3+2];
            const float sx = d0*c0 + d1*c3 + d2*c6;
            const float sy = d0*c1 + d1*c4 + d2*c7;
            const float sz = d0*c2 + d1*c5 + d2*c8;
            const float dx = probe_xyz[(size_t)ip*3+0] - (atom_xyz[(size_t)ia*3+0] + sx);
            const float dy = probe_xyz[(size_t)ip*3+1] - (atom_xyz[(size_t)ia*3+1] + sy);
            const float dz = probe_xyz[(size_t)ip*3+2] - (atom_xyz[(size_t)ia*3+2] + sz);
            const float dist = sqrtf(dx*dx + dy*dy + dz*dz);
            const float inv  = 1.f / (dist + 1e-8f);
            const float base = dist * (PI_F / CUTOFF_F);
            ushort4 eb;
            eb.x = f2bf(__sinf(base * (float)(q*4 + 1)) * inv);
            eb.y = f2bf(__sinf(base * (float)(q*4 + 2)) * inv);
            eb.z = f2bf(__sinf(base * (float)(q*4 + 3)) * inv);
            eb.w = f2bf(__sinf(base * (float)(q*4 + 4)) * inv);
            *(ushort4*)&epi_b[slot*40 + q*4] = eb;
            if (q == 0){
                ai_l[slot] = ia;
                pp_l[slot] = ip;
                float cw = (dist < CUTOFF_F) ? 0.5f * (__cosf(base) + 1.f) : 0.f;
                rc4_l[slot] = (float4){dx*inv, dy*inv, dz*inv, cw};
            }
        }
        __syncthreads();

        f32x4v pacc[2][4];
        #pragma unroll
        for (int mt = 0; mt < 2; mt++)
            #pragma unroll
            for (int nt = 0; nt < 4; nt++) pacc[mt][nt] = (f32x4v){0.f,0.f,0.f,0.f};
        #pragma unroll
        for (int mt = 0; mt < 2; mt++){
            const bf16x8 af = *(const bf16x8*)&epi_b[(mt*16 + lm)*40 + lq*8];
            #pragma unroll
            for (int nt = 0; nt < 4; nt++)
                pacc[mt][nt] = __builtin_amdgcn_mfma_f32_16x16x32_bf16(af, w1afr[nt], pacc[mt][nt], 0, 0, 0);
        }

        #pragma unroll
        for (int mt = 0; mt < 2; mt++){
            #pragma unroll
            for (int r = 0; r < 4; r++){
                const int e = mt*16 + lq*4 + r;
                const int i = ai_l[e];
                const float4 rc = rc4_l[e];
                const float* up = UT4 + ((size_t)i << 10);
                #pragma unroll
                for (int nt = 0; nt < 4; nt++){
                    const int col = w*64 + nt*16 + lm;
                    const float4 ut = *(const float4*)(up + (size_t)col * 4);
                    float z = pacc[mt][nt][r] + ut.w;
                    z = fmaf(rc.x, ut.x, fmaf(rc.y, ut.y, fmaf(rc.z, ut.z, z)));
                    const int wofs = e*512 + ((col*2) ^ ((e & 7) << 4));
                    *(unsigned short*)(xbase + wofs) = f2bf(silu_f(z));
                }
            }
        }
        __syncthreads();

        f32x4v acc00 = {0.f,0.f,0.f,0.f}, acc01 = {0.f,0.f,0.f,0.f};
        f32x4v acc10 = {0.f,0.f,0.f,0.f}, acc11 = {0.f,0.f,0.f,0.f};
        const int eA0 = lm;
        const int eA1 = 16 + lm;
        #pragma unroll
        for (int kb = 0; kb < 8; kb++){
            const int ko = kb*64 + lq*16;
            bf16x8 af0 = *(const bf16x8*)(xbase + eA0*512 + (ko ^ ((eA0 & 7) << 4)));
            bf16x8 af1 = *(const bf16x8*)(xbase + eA1*512 + (ko ^ ((eA1 & 7) << 4)));
            acc00 = __builtin_amdgcn_mfma_f32_16x16x32_bf16(af0, bfr[0][kb], acc00, 0, 0, 0);
            acc01 = __builtin_amdgcn_mfma_f32_16x16x32_bf16(af0, bfr[1][kb], acc01, 0, 0, 0);
            acc10 = __builtin_amdgcn_mfma_f32_16x16x32_bf16(af1, bfr[0][kb], acc10, 0, 0, 0);
            acc11 = __builtin_amdgcn_mfma_f32_16x16x32_bf16(af1, bfr[1][kb], acc11, 0, 0, 0);
        }

        float pr0[4], pr1[4];
        #pragma unroll
        for (int r = 0; r < 4; r++){
            pr0[r] = silu_f(acc00[r] + b2v0) * w3v0 + silu_f(acc01[r] + b2v1) * w3v1;
            pr1[r] = silu_f(acc10[r] + b2v0) * w3v0 + silu_f(acc11[r] + b2v1) * w3v1;
        }
        #pragma unroll
        for (int r = 0; r < 4; r++){
            #pragma unroll
            for (int m = 8; m >= 1; m >>= 1){
                pr0[r] += __shfl_xor(pr0[r], m, 64);
                pr1[r] += __shfl_xor(pr1[r], m, 64);
            }
        }
        if (lm == 0){
            #pragma unroll
            for (int r = 0; r < 4; r++){
                part[w][lq*4 + r]      = pr0[r];
                part[w][16 + lq*4 + r] = pr1[r];
            }
        }
        __syncthreads();

        if (t < 32 && (e0b + t) < E){
            float tot = part[0][t] + part[1][t] + part[2][t] + part[3][t] + b3;
            atomicAdd(&rho[pp_l[t]], tot * rc4_l[t].w);
        }
        __syncthreads();
    }
}

extern "C" void kernel_launch(void* const* d_in, const int* in_sizes, int n_in,
                              void* d_out, int out_size, void* d_ws, size_t ws_size,
                              hipStream_t stream)
{
    const float* s_stack   = (const float*)d_in[0];
    const float* v_stack   = (const float*)d_in[1];
    const float* atom_xyz  = (const float*)d_in[2];
    const float* probe_xyz = (const float*)d_in[3];
    const float* cell      = (const float*)d_in[4];
    const float* disp      = (const float*)d_in[5];
    const float* attn_w1   = (const float*)d_in[6];
    const float* attn_b1   = (const float*)d_in[7];
    const float* attn_w2   = (const float*)d_in[8];
    const float* msg_w1    = (const float*)d_in[10];
    const float* msg_b1    = (const float*)d_in[11];
    const float* msg_w2    = (const float*)d_in[12];
    const float* msg_b2    = (const float*)d_in[13];
    const float* msg_w3    = (const float*)d_in[14];
    const float* msg_b3    = (const float*)d_in[15];
    const int*   pe        = (const int*)d_in[16];

    const int N = in_sizes[0] / (L_DIM * F_DIM);
    const int E = in_sizes[16] / 2;
    const int P = out_size;
    const size_t NF = (size_t)N * F_DIM;

    float* ws = (float*)d_ws;
    unsigned short* VJKb = (unsigned short*)ws;            // 3N x 256 bf16
    unsigned short* NISb = VJKb + 3*NF;                    // N x 512 bf16
    float* UT4 = ws + (5*NF)/2;                            // N x 256 x 4 f32
    unsigned short* w1bt  = (unsigned short*)(ws + (13*NF)/2);
    unsigned short* w1cdt = w1bt + 65536;
    unsigned short* w2t   = w1cdt + 131072;
    unsigned short* wA1t  = w2t + 32768;
    int* cnt  = (int*)(wA1t + 32768);
    int* pos  = cnt + N;
    int* offs = pos + N;
    int* perm = offs + N + 1;

    const int prepElems = 262144 + 32768 + 2 * N;
    kPrep<<<(prepElems + 255) / 256, 256, 0, stream>>>(
        msg_w1, msg_w2, attn_w1, w1bt, w1cdt, w2t, wA1t,
        (float*)d_out, P, cnt, 2 * N);

    // kAW includes the hist tail (cnt zeroed by kPrep)
    kAW<<<(N + 7) / 8, 256, 0, stream>>>(s_stack, v_stack, wA1t, attn_b1, attn_w2,
                                         VJKb, NISb, pe, cnt, E, N);

    kScan<<<1, 1024, 0, stream>>>(cnt, offs, N);

    // kA2 includes the scatter tail (needs offs from kScan)
    const int gU  = (3 * N) / 128;                         // 192
    const int gT  = (N / 128) * 2;                         // 128
    const int gUT = gU + gT;
    const int gS  = (E + 255) / 256;                       // 512
    kA2<<<gUT + gS, 256, 0, stream>>>(VJKb, w1bt, NISb, w1cdt, msg_b1, UT4,
                                      pe, offs, pos, perm, E, gU, gUT);

    kB1<<<(E + 127) / 128, 256, 0, stream>>>(pe, disp, cell, atom_xyz, probe_xyz,
                                             UT4, msg_w1,
                                             w2t, msg_b2, msg_w3, msg_b3,
                                             perm, (float*)d_out, E);
}